// Round 7
// baseline (189.733 us; speedup 1.0000x reference)
//
#include <hip/hip_runtime.h>
#include <math.h>

static constexpr int kM = 80;
static constexpr int kT = 4000;
static constexpr int kB = 64;
static constexpr int kLow = kM / 3;                 // 26
static constexpr int kHighStart = 2 * kM / 3;       // 53
static constexpr int kHighCount = kM - kHighStart;  // 27
static constexpr int kTrunc = 12;                   // A_ns^12 = 0.95^192 ~ 5e-5
static constexpr int kRowsPerBlock = 4;             // persistent ping-pong depth
#define EPSF 1e-6f
#define LOG2E 1.4426950408889634f

typedef float vfloat4 __attribute__((ext_vector_type(4)));
typedef float vfloat2 __attribute__((ext_vector_type(2)));

__device__ __forceinline__ float hw_exp2(float x) { return __builtin_amdgcn_exp2f(x); }
__device__ __forceinline__ float hw_log2(float x) { return __builtin_amdgcn_logf(x); }

__device__ __forceinline__ float fast_sigmoid(float x) {
    return __builtin_amdgcn_rcpf(1.0f + hw_exp2(-x * LOG2E));
}

// ---------------- Kernel A: gate[b,t] — quarter-split, full occupancy -------
// Block = 256 thr = 64 float2-columns x 4 channel-quarters (wave q owns
// m in [20q, 20q+20)). 20 independent float2 loads/thread (wave = 64 x 8 B
// = 512 B/instr). 4-plane LDS exchange (8 KB), wave 0 finalizes.
// grid (32, 64) = 2048 blocks x 4 waves -> 8 blocks/CU = 32 waves/CU (max).
__global__ __launch_bounds__(256) void gate_kernel(
    const float* __restrict__ mel,
    const float* __restrict__ gate_temp,
    float* __restrict__ gate)
{
    const int tid = threadIdx.x;
    const int c   = tid & 63;           // float2-column within block
    const int q   = tid >> 6;           // channel quarter == wave id
    const int b   = blockIdx.y;
    const int col = blockIdx.x * 64 + c;            // float2-column index
    const bool valid = (col < kT / 2);              // last block: 48 idle cols

    const float* base = mel + (size_t)b * kM * kT + (size_t)col * 2;
    const int m0 = q * 20;

    vfloat2 slog = {0.f,0.f}, ssum = {0.f,0.f};
    vfloat2 slow = {0.f,0.f}, shigh = {0.f,0.f};
    if (valid) {
        #pragma unroll
        for (int j = 0; j < 20; ++j) {
            const int m = m0 + j;
            const vfloat2 v = *reinterpret_cast<const vfloat2*>(base + (size_t)m * kT);
            vfloat2 lg;
            lg.x = hw_log2(v.x + 1e-8f);
            lg.y = hw_log2(v.y + 1e-8f);
            slog += lg;
            ssum += v;
            if (m < kLow)        slow  += v;   // wave-uniform (scalar) branch
            if (m >= kHighStart) shigh += v;
        }
    }

    __shared__ vfloat2 p[4][4][64];     // [quarter][plane][col] = 8 KB
    p[q][0][c] = slog;
    p[q][1][c] = ssum;
    p[q][2][c] = slow;
    p[q][3][c] = shigh;
    __syncthreads();

    if (q == 0 && valid) {
        const vfloat2 tlog  = p[0][0][c] + p[1][0][c] + p[2][0][c] + p[3][0][c];
        const vfloat2 tsum  = p[0][1][c] + p[1][1][c] + p[2][1][c] + p[3][1][c];
        const vfloat2 tlow  = p[0][2][c] + p[1][2][c] + p[2][2][c] + p[3][2][c];
        const vfloat2 thigh = p[0][3][c] + p[1][3][c] + p[2][3][c] + p[3][3][c];

        const float gt = gate_temp[0];
        vfloat2 o;
        #pragma unroll
        for (int w = 0; w < 2; ++w) {
            const float sl = (w == 0) ? tlog.x  : tlog.y;
            const float ss = (w == 0) ? tsum.x  : tsum.y;
            const float lo = (w == 0) ? tlow.x  : tlow.y;
            const float hi = (w == 0) ? thigh.x : thigh.y;
            const float geo   = hw_exp2(sl * (1.0f / kM));
            const float arith = ss * (1.0f / kM) + 1e-8f;
            float sf = geo * __builtin_amdgcn_rcpf(arith);
            sf = fminf(fmaxf(sf, 0.0f), 1.0f);
            const float low  = lo * (1.0f / kLow);
            const float high = hi * (1.0f / kHighCount);
            float tilt = low * __builtin_amdgcn_rcpf(low + high + 1e-8f);
            tilt = fminf(fmaxf(tilt, 0.0f), 1.0f);
            const float sfa = sf + (1.0f - sf) * fmaxf(tilt - 0.6f, 0.0f);
            const float g = fast_sigmoid(gt * (sfa - 0.5f));
            if (w == 0) o.x = g; else o.y = g;
        }
        *reinterpret_cast<vfloat2*>(gate + (size_t)b * kT + (size_t)col * 2) = o;
    }
}

// ---------------- Kernel B: dual PCEN — persistent blocks, prefetch pipeline
// 1280 blocks x 4 rows each (5 blocks/CU, ALL co-resident, no tail).
// Ping-pong xA/xB: next row's 4x float4 loads are issued BEFORE the current
// row's trans-heavy compute, so HBM stays busy during the compute window
// (the duty-cycle stall that capped R2-R6 at ~2.8 TB/s).
// Carry per row via data-independent chunk transform (A = a^16 const):
//   carry_i = sum_{k<12} A^k B_{i-1-k} (+ A^i x0 exactly for i<=12).
__global__ __launch_bounds__(256) void pcen_kernel(
    const float* __restrict__ mel,
    const float* __restrict__ ls_ns, const float* __restrict__ la_ns,
    const float* __restrict__ ld_ns, const float* __restrict__ lr_ns,
    const float* __restrict__ ls_st, const float* __restrict__ la_st,
    const float* __restrict__ ld_st, const float* __restrict__ lr_st,
    const float* __restrict__ gate,
    float* __restrict__ out)
{
    const int i  = threadIdx.x;         // chunk index within row
    const int t0 = i * 16;
    const bool valid = (t0 < kT);       // tids 250..255 idle (barriers uniform)

    __shared__ vfloat2 Btab[256];
    __shared__ float sv0;

    float xA[16], xB[16];
    const int r0 = blockIdx.x * kRowsPerBlock;

    auto load_x = [&](float* x, int row) {
        if (valid) {
            const float4* p = reinterpret_cast<const float4*>(mel + (size_t)row * kT + t0);
            #pragma unroll
            for (int u = 0; u < 4; ++u) {
                const float4 v = p[u];
                x[4*u+0] = v.x; x[4*u+1] = v.y; x[4*u+2] = v.z; x[4*u+3] = v.w;
            }
        } else {
            #pragma unroll
            for (int k = 0; k < 16; ++k) x[k] = 0.0f;
        }
    };

    auto process = [&](const float* x, int row) {
        const int b = row / kM;
        const int m = row - b * kM;

        // per-row params (block-uniform; L2-resident after first touch)
        const float s_ns     = fminf(fmaxf(fast_sigmoid(ls_ns[m]), 0.05f), 0.3f);
        const float alpha_ns = fminf(fmaxf(fast_sigmoid(la_ns[m]), 0.9f), 0.999f);
        const float delta_ns = fminf(fmaxf(hw_exp2(ld_ns[m] * LOG2E), 0.5f), 5.0f);
        const float r_ns     = fminf(fmaxf(fast_sigmoid(lr_ns[m]), 0.05f), 0.25f);
        const float s_st     = fminf(fmaxf(fast_sigmoid(ls_st[m]), 0.05f), 0.3f);
        const float alpha_st = fminf(fmaxf(fast_sigmoid(la_st[m]), 0.9f), 0.999f);
        const float delta_st = fminf(fmaxf(hw_exp2(ld_st[m] * LOG2E), 0.001f), 0.1f);
        const float r_st     = fminf(fmaxf(fast_sigmoid(lr_st[m]), 0.05f), 0.25f);
        const float dr_ns = hw_exp2(r_ns * hw_log2(delta_ns));   // delta^r
        const float dr_st = hw_exp2(r_st * hw_log2(delta_st));

        const vfloat2 a2 = {1.0f - s_ns, 1.0f - s_st};
        const vfloat2 s2 = {s_ns, s_st};
        const vfloat2 d2 = {delta_ns, delta_st};
        const float man = -alpha_ns, mas = -alpha_st;

        // gate row loads (1 MB total -> L2-resident; latency hides under
        // the B-chain + barriers + compose below)
        float gv[16];
        if (valid) {
            const float4* gp = reinterpret_cast<const float4*>(gate + (size_t)b * kT + t0);
            #pragma unroll
            for (int u = 0; u < 4; ++u) {
                const float4 v = gp[u];
                gv[4*u+0] = v.x; gv[4*u+1] = v.y; gv[4*u+2] = v.z; gv[4*u+3] = v.w;
            }
        } else {
            #pragma unroll
            for (int k = 0; k < 16; ++k) gv[k] = 0.0f;
        }

        // chunk offset B_i (x is zeroed for invalid threads)
        vfloat2 Bv = {0.0f, 0.0f};
        #pragma unroll
        for (int k = 0; k < 16; ++k) {
            Bv = a2 * Bv + s2 * x[k];   // v_pk_fma_f32
        }
        const vfloat2 p2 = a2 * a2;
        const vfloat2 p4 = p2 * p2;
        const vfloat2 p8 = p4 * p4;
        const vfloat2 A2 = p8 * p8;     // a^16 (data-independent)

        __syncthreads();                // prior row's Btab reads complete
        Btab[i] = Bv;
        if (i == 0) sv0 = x[0];
        __syncthreads();

        // carry: sm = sum_{k<12} A^k B_{i-1-k} (+ A^i x0 exactly if i<=12)
        vfloat2 sm = {0.0f, 0.0f};
        vfloat2 pw = {1.0f, 1.0f};
        #pragma unroll
        for (int k = 0; k < kTrunc; ++k) {
            const vfloat2 Bk = Btab[(i - 1 - k) & 255];
            if (k < i) {
                sm = pw * Bk + sm;
                pw = pw * A2;
            }
        }
        if (i <= kTrunc) {
            const float x0 = sv0;
            const vfloat2 x02 = {x0, x0};
            sm = pw * x02 + sm;         // pw = A^i here; exact init term
        }

        // main pass: serial recurrence peeled off 8 independent trans chains
        if (valid) {
            float4* op = reinterpret_cast<float4*>(out + (size_t)row * kT + t0);
            #pragma unroll
            for (int h = 0; h < 2; ++h) {
                vfloat2 smv[8];
                #pragma unroll
                for (int j = 0; j < 8; ++j) {
                    sm = a2 * sm + s2 * x[8*h + j];    // v_pk_fma_f32
                    smv[j] = sm;
                }
                float res[8];
                #pragma unroll
                for (int j = 0; j < 8; ++j) {
                    const int k = 8*h + j;
                    const float xv = x[k];
                    vfloat2 g2;
                    g2.x = hw_exp2(man * hw_log2(smv[j].x + EPSF));
                    g2.y = hw_exp2(mas * hw_log2(smv[j].y + EPSF));
                    const vfloat2 u2 = g2 * xv + d2;   // v_pk_fma_f32
                    const float on = hw_exp2(r_ns * hw_log2(u2.x)) - dr_ns;
                    const float os = hw_exp2(r_st * hw_log2(u2.y)) - dr_st;
                    res[j] = fmaf(gv[k], os - on, on);
                }
                #pragma unroll
                for (int u = 0; u < 2; ++u) {
                    float4 v;
                    v.x = res[4*u+0]; v.y = res[4*u+1];
                    v.z = res[4*u+2]; v.w = res[4*u+3];
                    op[2*h + u] = v;                    // plain cached stores
                }
            }
        }
    };

    // statically-unrolled ping-pong: prefetch row k+1 before computing row k
    load_x(xA, r0 + 0);
    load_x(xB, r0 + 1);
    process(xA, r0 + 0);
    load_x(xA, r0 + 2);
    process(xB, r0 + 1);
    load_x(xB, r0 + 3);
    process(xA, r0 + 2);
    process(xB, r0 + 3);
}

extern "C" void kernel_launch(void* const* d_in, const int* in_sizes, int n_in,
                              void* d_out, int out_size, void* d_ws, size_t ws_size,
                              hipStream_t stream)
{
    const float* mel       = (const float*)d_in[0];
    const float* ls_ns     = (const float*)d_in[1];
    const float* la_ns     = (const float*)d_in[2];
    const float* ld_ns     = (const float*)d_in[3];
    const float* lr_ns     = (const float*)d_in[4];
    const float* ls_st     = (const float*)d_in[5];
    const float* la_st     = (const float*)d_in[6];
    const float* ld_st     = (const float*)d_in[7];
    const float* lr_st     = (const float*)d_in[8];
    const float* gate_temp = (const float*)d_in[9];
    float* out  = (float*)d_out;
    float* gate = (float*)d_ws;   // kB*kT floats = 1.02 MB scratch

    dim3 gA((kT / 2 + 63) / 64, kB);     // (32, 64) = 2048 blocks, 32 waves/CU
    gate_kernel<<<gA, 256, 0, stream>>>(mel, gate_temp, gate);

    const int nblk = kB * kM / kRowsPerBlock;   // 1280 blocks = 5 blocks/CU
    pcen_kernel<<<dim3(nblk), 256, 0, stream>>>(mel, ls_ns, la_ns, ld_ns, lr_ns,
                                                ls_st, la_st, ld_st, lr_st, gate, out);
}